// Round 12
// baseline (105.654 us; speedup 1.0000x reference)
//
#include <hip/hip_runtime.h>
#include <stdint.h>

using bf16x8 = __attribute__((ext_vector_type(8))) short;
using f32x4  = __attribute__((ext_vector_type(4))) float;

#define DEVINL __device__ __forceinline__

DEVINL unsigned short f2bf(float f) {
  union { float f; unsigned u; } v; v.f = f;
  unsigned u = v.u;
  return (unsigned short)((u + 0x7FFFu + ((u >> 16) & 1u)) >> 16);
}
DEVINL float bf2f(unsigned short h) {
  union { unsigned u; float f; } v; v.u = ((unsigned)h) << 16;
  return v.f;
}

DEVINL void gload_lds16(const void* g, void* l) {
  __builtin_amdgcn_global_load_lds(
      (const __attribute__((address_space(1))) void*)g,
      (__attribute__((address_space(3))) void*)l, 16, 0, 0);
}

// ---------------------------------------------------------------------------
// 256x128 bf16 GEMM tile, 8 waves (4M x 2N), BK=64, depth-2 ring, 96 KB LDS.
// Staged bytes per 4.2 MFLOP iter = 48 KB (87 FLOP/B, 1.33x the 128^2 core) —
// attacks the measured L2->LDS staging bound. Per-wave fragment code identical
// to the round-8 proven core (64x64 out, T2 XOR swizzle via pre-swizzled
// GLOBAL source chunk, LDS dest linear, bank conflicts measured 0; raw
// s_barrier + counted vmcnt(6)).
// A (row-major bf16, ld=K), B (row-major bf16, ld=K), C = A·B^T (+bias).
// ---------------------------------------------------------------------------
template<int OUT_BF16, int HAS_BIAS>
DEVINL void gemm_core(const unsigned short* __restrict__ A,
                      const unsigned short* __restrict__ B,
                      void* __restrict__ C,
                      const float* __restrict__ bias,
                      int K, int Cld, int arow0, int brow0, int crow0, int ccol0)
{
  __shared__ __align__(16) unsigned short As[2][256 * 64];   // 64 KB
  __shared__ __align__(16) unsigned short Bs[2][128 * 64];   // 32 KB

  const int t    = threadIdx.x;        // 0..511
  const int wave = t >> 6;             // 0..7
  const int lane = t & 63;
  const int wr   = (wave >> 1) << 6;   // 0,64,128,192
  const int wc   = (wave & 1) << 6;    // 0,64
  const int lrow = lane & 15;
  const int kg   = lane >> 4;          // 0..3

  f32x4 acc[4][4];
#pragma unroll
  for (int r = 0; r < 4; ++r)
#pragma unroll
    for (int q = 0; q < 4; ++q) acc[r][q] = (f32x4){0.f, 0.f, 0.f, 0.f};

  // staging: 512 thr x 16B = 8 KB/pass; A: 4 passes (256 rows), B: 2 (128 rows)
  // pre-swizzled global source chunk: chunk_phys = chunk ^ (row&7); pass
  // stride 64 rows keeps row&7 invariant.
  const int srow = t >> 3;                                  // 0..63
  const int scol = (((t & 7) ^ (srow & 7)) << 3);
  const unsigned short* aSrc = A + (size_t)(arow0 + srow) * K + scol;
  const unsigned short* bSrc = B + (size_t)(brow0 + srow) * K + scol;

  const int nt = K >> 6;
  {  // prologue: stage tile 0 -> buffer 0 (6 gload_lds per wave)
    char* aD = (char*)As[0] + wave * 1024;
    char* bD = (char*)Bs[0] + wave * 1024;
#pragma unroll
    for (int p = 0; p < 4; ++p)
      gload_lds16(aSrc + (size_t)(p * 64) * K, aD + p * 8192);
#pragma unroll
    for (int p = 0; p < 2; ++p)
      gload_lds16(bSrc + (size_t)(p * 64) * K, bD + p * 8192);
  }
  // swizzled read chunk offsets (elements): chunk = (kg + kk/8) ^ (row&7)
  const int rs = lrow & 7;
  const int cA0 = ((kg + 0) ^ rs) << 3;   // kk = 0
  const int cA1 = ((kg + 4) ^ rs) << 3;   // kk = 32

  int cur = 0;
  for (int tt = 0; tt < nt; ++tt) {
    if (tt + 1 < nt) {                 // issue next tile's 6, wait for current 6
      const int k0 = (tt + 1) << 6;
      char* aD = (char*)As[cur ^ 1] + wave * 1024;
      char* bD = (char*)Bs[cur ^ 1] + wave * 1024;
#pragma unroll
      for (int p = 0; p < 4; ++p)
        gload_lds16(aSrc + (size_t)(p * 64) * K + k0, aD + p * 8192);
#pragma unroll
      for (int p = 0; p < 2; ++p)
        gload_lds16(bSrc + (size_t)(p * 64) * K + k0, bD + p * 8192);
      asm volatile("s_waitcnt vmcnt(6)" ::: "memory");
    } else {
      asm volatile("s_waitcnt vmcnt(0)" ::: "memory");
    }
    asm volatile("s_barrier" ::: "memory");
    const unsigned short* Ab = As[cur];
    const unsigned short* Bb = Bs[cur];
#pragma unroll
    for (int kk = 0; kk < 64; kk += 32) {
      const int cofs = (kk == 0) ? cA0 : cA1;
      bf16x8 af[4], bq[4];
#pragma unroll
      for (int r = 0; r < 4; ++r)
        af[r] = *(const bf16x8*)&Ab[(wr + r * 16 + lrow) * 64 + cofs];
#pragma unroll
      for (int q = 0; q < 4; ++q)
        bq[q] = *(const bf16x8*)&Bb[(wc + q * 16 + lrow) * 64 + cofs];
#pragma unroll
      for (int r = 0; r < 4; ++r)
#pragma unroll
        for (int q = 0; q < 4; ++q)
          acc[r][q] = __builtin_amdgcn_mfma_f32_16x16x32_bf16(af[r], bq[q], acc[r][q], 0, 0, 0);
    }
    asm volatile("s_barrier" ::: "memory");  // all waves done reading buf cur
    cur ^= 1;
  }

  // epilogue: C/D layout col=lane&15, row=(lane>>4)*4+v  [m89/m91 verified]
#pragma unroll
  for (int r = 0; r < 4; ++r) {
#pragma unroll
    for (int q = 0; q < 4; ++q) {
      const int col = ccol0 + wc + q * 16 + lrow;
      const float bv = HAS_BIAS ? bias[col] : 0.f;
#pragma unroll
      for (int v = 0; v < 4; ++v) {
        const int row = crow0 + wr + r * 16 + (kg << 2) + v;
        const float val = acc[r][q][v] + bv;
        if (OUT_BF16)
          ((unsigned short*)C)[(size_t)row * Cld + col] = f2bf(val);
        else
          ((float*)C)[(size_t)row * Cld + col] = val;
      }
    }
  }
}

// ---------------------------------------------------------------------------
// mega1 (208 blocks x 512 thr):
//  bids 0..159  -> H0p[p] = XR[m(p)] @ w1cat[j(p)]^T  (20 pairs x 2 rt x 4 ct)
//  bids 160..207 -> W2EN_s = WEN @ w2t_s^T            (4 s x 3 rt x 4 ct)
// ---------------------------------------------------------------------------
__global__ __launch_bounds__(512) void mega1_k(const unsigned short* __restrict__ xrb,
                                               const unsigned short* __restrict__ w1cat,
                                               const unsigned short* __restrict__ wen,
                                               const unsigned short* __restrict__ w2t,
                                               unsigned short* __restrict__ H0p,
                                               unsigned short* __restrict__ W2EN) {
  const int bid = blockIdx.x;
  if (bid < 160) {
    const int p = bid >> 3, q = bid & 7;
    const int rt = q >> 2, ct = q & 3;      // rt: 256-row tile, ct: 128-col tile
    const int MM[20] = {0,1,2,3, 0,1,2, 1,2,3, 0,1, 1,2, 2,3, 0,1,2,3};
    const int JJ[20] = {0,0,0,0, 1,1,1, 2,2,2, 3,3, 4,4, 5,5, 6,7,8,9};
    gemm_core<1, 0>(xrb, w1cat, H0p, nullptr, 2048, 512,
                    MM[p] * 512 + rt * 256, JJ[p] * 512 + ct * 128,
                    p * 512 + rt * 256, ct * 128);
  } else {
    const int b2 = bid - 160;
    const int s = b2 / 12, r = b2 % 12;
    const int rt = r >> 2, ct = r & 3;      // rt 0..2 (768 rows), ct 0..3
    gemm_core<1, 0>(wen, w2t, W2EN, nullptr, 2048, 512,
                    rt * 256, s * 512 + ct * 128,
                    s * 768 + rt * 256, ct * 128);
  }
}

// gemmF: EN0 = h1(7680x512) @ W2EN_s^T + ENb_s   (fp32 out, 768 cols)
__global__ __launch_bounds__(512) void gemmF_k(const unsigned short* __restrict__ h1,
                                               const unsigned short* __restrict__ W2EN,
                                               const float* __restrict__ ENb,
                                               float* __restrict__ EN0) {
  const int y = blockIdx.y;                  // 0..29 row tiles of 256
  const int c = y >> 1;                      // subset index (512 rows each)
  const int s = (c < 4) ? 1 : (c < 10) ? 2 : (c < 14) ? 3 : 4;
  gemm_core<0, 1>(h1, W2EN, EN0, ENb + (size_t)(s - 1) * 768, 512, 768,
                  y * 256, (s - 1) * 768 + blockIdx.x * 128,
                  y * 256, blockIdx.x * 128);
}

// ---------------------------------------------------------------------------
// prep kernels (round-5 proven versions)
// ---------------------------------------------------------------------------
__global__ __launch_bounds__(256) void prep_xr(const float* __restrict__ x,
                                               unsigned short* __restrict__ xrb) {
  const int tid = blockIdx.x * 256 + threadIdx.x;   // 1,048,576
  const int r = tid >> 9;                           // row = m*512+b
  const int k = (tid & 511) << 2;
  const int m = r >> 9, b = r & 511;
  const float4 vv = *(const float4*)(x + ((size_t)(b * 4 + m)) * 2048 + k);
  ushort4 o;
  o.x = f2bf(fmaxf(vv.x, 0.f)); o.y = f2bf(fmaxf(vv.y, 0.f));
  o.z = f2bf(fmaxf(vv.z, 0.f)); o.w = f2bf(fmaxf(vv.w, 0.f));
  *(ushort4*)(xrb + (size_t)r * 2048 + k) = o;
}

__global__ __launch_bounds__(256) void prep_w1cat(const float* w11, const float* w12,
                                                  const float* w13, const float* w14,
                                                  unsigned short* __restrict__ w1cat) {
  const int tid = blockIdx.x * 256 + threadIdx.x;   // 2,621,440
  const int r = tid >> 9;                           // 0..5119 = j*512+o
  const int k = (tid & 511) << 2;
  const int j = r >> 9, o = r & 511;
  const float* src; int s, tt;
  if (j == 0)      { src = w11; s = 1; tt = 0; }
  else if (j < 3)  { src = w12; s = 2; tt = j - 1; }
  else if (j < 6)  { src = w13; s = 3; tt = j - 3; }
  else             { src = w14; s = 4; tt = j - 6; }
  const float4 vv = *(const float4*)(src + (size_t)o * (s * 2048) + tt * 2048 + k);
  ushort4 ov;
  ov.x = f2bf(vv.x); ov.y = f2bf(vv.y); ov.z = f2bf(vv.z); ov.w = f2bf(vv.w);
  *(ushort4*)(w1cat + (size_t)r * 2048 + k) = ov;
}

// transpose w2_s (2048 x 512 f32) -> w2t[s] (512 x 2048 bf16), 64x64 LDS tiles
__global__ __launch_bounds__(256) void prep_w2t(const float* w21, const float* w22,
                                                const float* w23, const float* w24,
                                                unsigned short* __restrict__ w2t) {
  __shared__ float lds[64][65];
  const int s = blockIdx.z, rt = blockIdx.y, ct = blockIdx.x;  // rt: o2/64 (32), ct: d/64 (8)
  const float* src = (s == 0) ? w21 : (s == 1) ? w22 : (s == 2) ? w23 : w24;
  const int tr = threadIdx.x >> 4;            // 0..15
  const int tc = (threadIdx.x & 15) << 2;     // 0..60
#pragma unroll
  for (int i = 0; i < 4; ++i) {
    const float4 v = *(const float4*)(src + (size_t)(rt * 64 + tr + 16 * i) * 512 + ct * 64 + tc);
    lds[tr + 16 * i][tc + 0] = v.x; lds[tr + 16 * i][tc + 1] = v.y;
    lds[tr + 16 * i][tc + 2] = v.z; lds[tr + 16 * i][tc + 3] = v.w;
  }
  __syncthreads();
#pragma unroll
  for (int i = 0; i < 4; ++i) {
    ushort4 ov;
    ov.x = f2bf(lds[tc + 0][tr + 16 * i]); ov.y = f2bf(lds[tc + 1][tr + 16 * i]);
    ov.z = f2bf(lds[tc + 2][tr + 16 * i]); ov.w = f2bf(lds[tc + 3][tr + 16 * i]);
    *(ushort4*)(w2t + ((size_t)s * 512 + ct * 64 + tr + 16 * i) * 2048 + rt * 64 + tc) = ov;
  }
}

__global__ __launch_bounds__(256) void prep_wen(const float* __restrict__ w_emb,
                                                const float* __restrict__ w_node,
                                                unsigned short* __restrict__ wen) {
  const int tid = blockIdx.x * 256 + threadIdx.x;   // 393,216
  const int r = tid >> 9;                           // 0..767
  const int k = (tid & 511) << 2;
  float4 vv = make_float4(0.f, 0.f, 0.f, 0.f);
  if (r < 300)       vv = *(const float4*)(w_emb + (size_t)r * 2048 + k);
  else if (r < 691)  vv = *(const float4*)(w_node + (size_t)(r - 300) * 2048 + k);
  ushort4 ov;
  ov.x = f2bf(vv.x); ov.y = f2bf(vv.y); ov.z = f2bf(vv.z); ov.w = f2bf(vv.w);
  *(ushort4*)(wen + (size_t)r * 2048 + k) = ov;
}

// ENb[s][e] = dot(WEN_row_e (f32 sources), b2_s)  — one wave per output
__global__ __launch_bounds__(256) void prep_enb(const float* __restrict__ wemb,
                                                const float* __restrict__ wnode,
                                                const float* b21, const float* b22,
                                                const float* b23, const float* b24,
                                                float* __restrict__ ENb) {
  const int w = blockIdx.x * 4 + (threadIdx.x >> 6);   // 0..3071
  const int lane = threadIdx.x & 63;
  const int s = w / 768, e = w % 768;
  const float* b2 = (s == 0) ? b21 : (s == 1) ? b22 : (s == 2) ? b23 : b24;
  float acc = 0.f;
  if (e < 691) {
    const float* row = (e < 300) ? (wemb + (size_t)e * 2048) : (wnode + (size_t)(e - 300) * 2048);
#pragma unroll
    for (int i = 0; i < 8; ++i) {
      const float4 a  = *(const float4*)(row + i * 256 + lane * 4);
      const float4 bb = *(const float4*)(b2  + i * 256 + lane * 4);
      acc += a.x * bb.x + a.y * bb.y + a.z * bb.z + a.w * bb.w;
    }
  }
#pragma unroll
  for (int off = 32; off; off >>= 1) acc += __shfl_down(acc, off);
  if (lane == 0) ENb[w] = acc;
}

// combine1: h1[c*512+b, o] = relu(b1_s[o] + sum_t H0p[P[c][t]*512 + b, o]) -> bf16
__global__ __launch_bounds__(128) void combine1_k(const unsigned short* __restrict__ H0p,
                                                  unsigned short* __restrict__ h1,
                                                  const float* __restrict__ b11,
                                                  const float* __restrict__ b12,
                                                  const float* __restrict__ b13,
                                                  const float* __restrict__ b14) {
  const int cb = blockIdx.x;            // 0..7679 = c*512+b
  const int c = cb >> 9, b = cb & 511;
  const int s = (c < 4) ? 1 : (c < 10) ? 2 : (c < 14) ? 3 : 4;
  const unsigned char P[15][4] = {
    {0,0,0,0},{1,0,0,0},{2,0,0,0},{3,0,0,0},
    {4,7,0,0},{4,8,0,0},{4,9,0,0},{5,8,0,0},{5,9,0,0},{6,9,0,0},
    {10,12,14,0},{10,12,15,0},{10,13,15,0},{11,13,15,0},
    {16,17,18,19}};
  const float* b1 = (s == 1) ? b11 : (s == 2) ? b12 : (s == 3) ? b13 : b14;
  const int o = threadIdx.x << 2;
  float4 a = *(const float4*)(b1 + o);
  for (int t = 0; t < s; ++t) {
    const int p = P[c][t];
    const ushort4 hv = *(const ushort4*)(H0p + ((size_t)(p * 512 + b)) * 512 + o);
    a.x += bf2f(hv.x); a.y += bf2f(hv.y); a.z += bf2f(hv.z); a.w += bf2f(hv.w);
  }
  ushort4 ov;
  ov.x = f2bf(fmaxf(a.x, 0.f)); ov.y = f2bf(fmaxf(a.y, 0.f));
  ov.z = f2bf(fmaxf(a.z, 0.f)); ov.w = f2bf(fmaxf(a.w, 0.f));
  *(ushort4*)(h1 + (size_t)cb * 512 + o) = ov;
}

// combine2 (round-5 proven): INCL-sum over subsets + write both outputs
__global__ __launch_bounds__(256) void combine2_k(const float* __restrict__ EN0,
                                                  const float* __restrict__ b_emb,
                                                  const float* __restrict__ b_node,
                                                  float* __restrict__ out0,
                                                  float* __restrict__ out1) {
  const int b   = blockIdx.x;
  const int col = blockIdx.y * 256 + threadIdx.x;
  if (col >= 691) return;
  float vals[15];
#pragma unroll
  for (int j = 0; j < 15; ++j)
    vals[j] = EN0[((size_t)(j * 512 + b)) * 768 + col];
  const int MSK[15] = {1,2,4,8,3,5,9,6,10,12,7,11,13,14,15};
  if (col < 300) {
    const float be = b_emb[col];
#pragma unroll
    for (int i = 0; i < 15; ++i) {
      float sum = be;
#pragma unroll
      for (int j = 0; j < 15; ++j)
        if ((MSK[j] & MSK[i]) == MSK[j]) sum += vals[j];
      out0[((size_t)b * 15 + i) * 300 + col] = sum;
    }
  } else {
    const int v = col - 300;
    const float bn = b_node[v];
#pragma unroll
    for (int i = 0; i < 15; ++i) {
      float sum = bn;
#pragma unroll
      for (int j = 0; j < 15; ++j)
        if ((MSK[j] & MSK[i]) == MSK[j]) sum += vals[j];
      out1[((size_t)b * 391 + v) * 15 + i] = sum;
    }
  }
}

// ---------------------------------------------------------------------------
extern "C" void kernel_launch(void* const* d_in, const int* in_sizes, int n_in,
                              void* d_out, int out_size, void* d_ws, size_t ws_size,
                              hipStream_t stream) {
  const float* x     = (const float*)d_in[0];
  const float* w11   = (const float*)d_in[1];
  const float* b11   = (const float*)d_in[2];
  const float* w21   = (const float*)d_in[3];
  const float* b21   = (const float*)d_in[4];
  const float* w12   = (const float*)d_in[5];
  const float* b12   = (const float*)d_in[6];
  const float* w22   = (const float*)d_in[7];
  const float* b22   = (const float*)d_in[8];
  const float* w13   = (const float*)d_in[9];
  const float* b13   = (const float*)d_in[10];
  const float* w23   = (const float*)d_in[11];
  const float* b23   = (const float*)d_in[12];
  const float* w14   = (const float*)d_in[13];
  const float* b14   = (const float*)d_in[14];
  const float* w24   = (const float*)d_in[15];
  const float* b24   = (const float*)d_in[16];
  const float* wemb  = (const float*)d_in[17];
  const float* bemb  = (const float*)d_in[18];
  const float* wnode = (const float*)d_in[19];
  const float* bnode = (const float*)d_in[20];

  char* ws = (char*)d_ws;
  // layout (bytes); EN0 aliases xrb+w1cat (dead after mega1). peak ~62.4 MB
  unsigned short* xrb   = (unsigned short*)(ws + 0);                 //  8,388,608
  unsigned short* w1cat = (unsigned short*)(ws + 8388608);           // 20,971,520 -> 29,360,128
  unsigned short* w2t   = (unsigned short*)(ws + 29360128);          //  8,388,608 -> 37,748,736
  unsigned short* wen   = (unsigned short*)(ws + 37748736);          //  3,145,728 -> 40,894,464
  unsigned short* H0p   = (unsigned short*)(ws + 40894464);          // 10,485,760 -> 51,380,224
  unsigned short* W2EN  = (unsigned short*)(ws + 51380224);          //  3,145,728 -> 54,525,952
  float*          ENb   = (float*)(ws + 54525952);                   //     12,288 -> 54,538,240
  unsigned short* h1bf  = (unsigned short*)(ws + 54538240);          //  7,864,320 -> 62,402,560
  float*          EN0   = (float*)(ws + 0);                          // 23,592,960 (aliases xrb/w1cat)

  float* out0 = (float*)d_out;            // embeddings (512,15,300)
  float* out1 = out0 + 2304000;           // node_out^T (512,391,15)

  prep_xr   <<<4096, 256, 0, stream>>>(x, xrb);
  prep_w1cat<<<10240, 256, 0, stream>>>(w11, w12, w13, w14, w1cat);
  prep_w2t  <<<dim3(8, 32, 4), 256, 0, stream>>>(w21, w22, w23, w24, w2t);
  prep_wen  <<<1536, 256, 0, stream>>>(wemb, wnode, wen);
  prep_enb  <<<768, 256, 0, stream>>>(wemb, wnode, b21, b22, b23, b24, ENb);

  mega1_k   <<<208, 512, 0, stream>>>(xrb, w1cat, wen, w2t, H0p, W2EN);
  combine1_k<<<7680, 128, 0, stream>>>(H0p, h1bf, b11, b12, b13, b14);
  gemmF_k   <<<dim3(6, 30), 512, 0, stream>>>(h1bf, W2EN, ENb, EN0);
  combine2_k<<<dim3(512, 3), 256, 0, stream>>>(EN0, bemb, bnode, out0, out1);
}

// Round 13
// 99.102 us; speedup vs baseline: 1.0661x; 1.0661x over previous
//
#include <hip/hip_runtime.h>
#include <stdint.h>

using bf16x8 = __attribute__((ext_vector_type(8))) short;
using f32x4  = __attribute__((ext_vector_type(4))) float;

#define DEVINL __device__ __forceinline__

DEVINL unsigned short f2bf(float f) {
  union { float f; unsigned u; } v; v.f = f;
  unsigned u = v.u;
  return (unsigned short)((u + 0x7FFFu + ((u >> 16) & 1u)) >> 16);
}
DEVINL float bf2f(unsigned short h) {
  union { unsigned u; float f; } v; v.u = ((unsigned)h) << 16;
  return v.f;
}

DEVINL void gload_lds16(const void* g, void* l) {
  __builtin_amdgcn_global_load_lds(
      (const __attribute__((address_space(1))) void*)g,
      (__attribute__((address_space(3))) void*)l, 16, 0, 0);
}

// ---------------------------------------------------------------------------
// Round-12 core (proven 49.9 µs): 256x128 bf16 GEMM tile, 8 waves (4M x 2N),
// BK=64, depth-2 ring, 96 KB LDS, T2 XOR swizzle via pre-swizzled GLOBAL
// source (LDS dest linear; bank conflicts measured 0), raw s_barrier +
// counted vmcnt(6).
// ---------------------------------------------------------------------------
template<int OUT_BF16, int HAS_BIAS>
DEVINL void gemm_core(const unsigned short* __restrict__ A,
                      const unsigned short* __restrict__ B,
                      void* __restrict__ C,
                      const float* __restrict__ bias,
                      int K, int Cld, int arow0, int brow0, int crow0, int ccol0)
{
  __shared__ __align__(16) unsigned short As[2][256 * 64];   // 64 KB
  __shared__ __align__(16) unsigned short Bs[2][128 * 64];   // 32 KB

  const int t    = threadIdx.x;        // 0..511
  const int wave = t >> 6;             // 0..7
  const int lane = t & 63;
  const int wr   = (wave >> 1) << 6;   // 0,64,128,192
  const int wc   = (wave & 1) << 6;    // 0,64
  const int lrow = lane & 15;
  const int kg   = lane >> 4;          // 0..3

  f32x4 acc[4][4];
#pragma unroll
  for (int r = 0; r < 4; ++r)
#pragma unroll
    for (int q = 0; q < 4; ++q) acc[r][q] = (f32x4){0.f, 0.f, 0.f, 0.f};

  const int srow = t >> 3;                                  // 0..63
  const int scol = (((t & 7) ^ (srow & 7)) << 3);
  const unsigned short* aSrc = A + (size_t)(arow0 + srow) * K + scol;
  const unsigned short* bSrc = B + (size_t)(brow0 + srow) * K + scol;

  const int nt = K >> 6;
  {  // prologue: stage tile 0 -> buffer 0 (6 gload_lds per wave)
    char* aD = (char*)As[0] + wave * 1024;
    char* bD = (char*)Bs[0] + wave * 1024;
#pragma unroll
    for (int p = 0; p < 4; ++p)
      gload_lds16(aSrc + (size_t)(p * 64) * K, aD + p * 8192);
#pragma unroll
    for (int p = 0; p < 2; ++p)
      gload_lds16(bSrc + (size_t)(p * 64) * K, bD + p * 8192);
  }
  const int rs = lrow & 7;
  const int cA0 = ((kg + 0) ^ rs) << 3;   // kk = 0
  const int cA1 = ((kg + 4) ^ rs) << 3;   // kk = 32

  int cur = 0;
  for (int tt = 0; tt < nt; ++tt) {
    if (tt + 1 < nt) {
      const int k0 = (tt + 1) << 6;
      char* aD = (char*)As[cur ^ 1] + wave * 1024;
      char* bD = (char*)Bs[cur ^ 1] + wave * 1024;
#pragma unroll
      for (int p = 0; p < 4; ++p)
        gload_lds16(aSrc + (size_t)(p * 64) * K + k0, aD + p * 8192);
#pragma unroll
      for (int p = 0; p < 2; ++p)
        gload_lds16(bSrc + (size_t)(p * 64) * K + k0, bD + p * 8192);
      asm volatile("s_waitcnt vmcnt(6)" ::: "memory");
    } else {
      asm volatile("s_waitcnt vmcnt(0)" ::: "memory");
    }
    asm volatile("s_barrier" ::: "memory");
    const unsigned short* Ab = As[cur];
    const unsigned short* Bb = Bs[cur];
#pragma unroll
    for (int kk = 0; kk < 64; kk += 32) {
      const int cofs = (kk == 0) ? cA0 : cA1;
      bf16x8 af[4], bq[4];
#pragma unroll
      for (int r = 0; r < 4; ++r)
        af[r] = *(const bf16x8*)&Ab[(wr + r * 16 + lrow) * 64 + cofs];
#pragma unroll
      for (int q = 0; q < 4; ++q)
        bq[q] = *(const bf16x8*)&Bb[(wc + q * 16 + lrow) * 64 + cofs];
#pragma unroll
      for (int r = 0; r < 4; ++r)
#pragma unroll
        for (int q = 0; q < 4; ++q)
          acc[r][q] = __builtin_amdgcn_mfma_f32_16x16x32_bf16(af[r], bq[q], acc[r][q], 0, 0, 0);
    }
    asm volatile("s_barrier" ::: "memory");
    cur ^= 1;
  }

  // epilogue: C/D layout col=lane&15, row=(lane>>4)*4+v  [m89/m91 verified]
#pragma unroll
  for (int r = 0; r < 4; ++r) {
#pragma unroll
    for (int q = 0; q < 4; ++q) {
      const int col = ccol0 + wc + q * 16 + lrow;
      const float bv = HAS_BIAS ? bias[col] : 0.f;
#pragma unroll
      for (int v = 0; v < 4; ++v) {
        const int row = crow0 + wr + r * 16 + (kg << 2) + v;
        const float val = acc[r][q][v] + bv;
        if (OUT_BF16)
          ((unsigned short*)C)[(size_t)row * Cld + col] = f2bf(val);
        else
          ((float*)C)[(size_t)row * Cld + col] = val;
      }
    }
  }
}

// ---------------------------------------------------------------------------
// mega1 (208 blocks x 512 thr) — round-12 exact.
// ---------------------------------------------------------------------------
__global__ __launch_bounds__(512) void mega1_k(const unsigned short* __restrict__ xrb,
                                               const unsigned short* __restrict__ w1cat,
                                               const unsigned short* __restrict__ wen,
                                               const unsigned short* __restrict__ w2t,
                                               unsigned short* __restrict__ H0p,
                                               unsigned short* __restrict__ W2EN) {
  const int bid = blockIdx.x;
  if (bid < 160) {
    const int p = bid >> 3, q = bid & 7;
    const int rt = q >> 2, ct = q & 3;
    const int MM[20] = {0,1,2,3, 0,1,2, 1,2,3, 0,1, 1,2, 2,3, 0,1,2,3};
    const int JJ[20] = {0,0,0,0, 1,1,1, 2,2,2, 3,3, 4,4, 5,5, 6,7,8,9};
    gemm_core<1, 0>(xrb, w1cat, H0p, nullptr, 2048, 512,
                    MM[p] * 512 + rt * 256, JJ[p] * 512 + ct * 128,
                    p * 512 + rt * 256, ct * 128);
  } else {
    const int b2 = bid - 160;
    const int s = b2 / 12, r = b2 % 12;
    const int rt = r >> 2, ct = r & 3;
    gemm_core<1, 0>(wen, w2t, W2EN, nullptr, 2048, 512,
                    rt * 256, s * 512 + ct * 128,
                    s * 768 + rt * 256, ct * 128);
  }
}

// gemmF: EN0 = h1(7680x512) @ W2EN_s^T + ENb_s   (fp32 out, 768 cols) — r12 exact
__global__ __launch_bounds__(512) void gemmF_k(const unsigned short* __restrict__ h1,
                                               const unsigned short* __restrict__ W2EN,
                                               const float* __restrict__ ENb,
                                               float* __restrict__ EN0) {
  const int y = blockIdx.y;                  // 0..29 row tiles of 256
  const int c = y >> 1;
  const int s = (c < 4) ? 1 : (c < 10) ? 2 : (c < 14) ? 3 : 4;
  gemm_core<0, 1>(h1, W2EN, EN0, ENb + (size_t)(s - 1) * 768, 512, 768,
                  y * 256, (s - 1) * 768 + blockIdx.x * 128,
                  y * 256, blockIdx.x * 128);
}

// ---------------------------------------------------------------------------
// prep_all: the 5 proven prep bodies in ONE dispatch (17664 blocks x 256 thr).
//  [0,10240)       w1cat cast      [10240,14336)  xr relu+cast
//  [14336,15360)   w2t transpose   [15360,16896)  wen build
//  [16896,17664)   enb v2: one block per e; row loaded once, 4 dots (6.3 MB
//                  traffic vs old 25 MB)
// ---------------------------------------------------------------------------
__global__ __launch_bounds__(256) void prep_all_k(const float* __restrict__ x,
                                                  const float* w11, const float* w12,
                                                  const float* w13, const float* w14,
                                                  const float* w21, const float* w22,
                                                  const float* w23, const float* w24,
                                                  const float* __restrict__ wemb,
                                                  const float* __restrict__ wnode,
                                                  const float* b21, const float* b22,
                                                  const float* b23, const float* b24,
                                                  unsigned short* __restrict__ xrb,
                                                  unsigned short* __restrict__ w1cat,
                                                  unsigned short* __restrict__ w2t,
                                                  unsigned short* __restrict__ wen,
                                                  float* __restrict__ ENb) {
  __shared__ float lds[64][65];
  __shared__ float red[4][4];
  const int bid = blockIdx.x;
  if (bid < 10240) {                    // ---- w1cat (round-5 body)
    const int tid = bid * 256 + threadIdx.x;
    const int r = tid >> 9;
    const int k = (tid & 511) << 2;
    const int j = r >> 9, o = r & 511;
    const float* src; int s, tt;
    if (j == 0)      { src = w11; s = 1; tt = 0; }
    else if (j < 3)  { src = w12; s = 2; tt = j - 1; }
    else if (j < 6)  { src = w13; s = 3; tt = j - 3; }
    else             { src = w14; s = 4; tt = j - 6; }
    const float4 vv = *(const float4*)(src + (size_t)o * (s * 2048) + tt * 2048 + k);
    ushort4 ov;
    ov.x = f2bf(vv.x); ov.y = f2bf(vv.y); ov.z = f2bf(vv.z); ov.w = f2bf(vv.w);
    *(ushort4*)(w1cat + (size_t)r * 2048 + k) = ov;
  } else if (bid < 14336) {             // ---- xr (round-5 body)
    const int tid = (bid - 10240) * 256 + threadIdx.x;
    const int r = tid >> 9;
    const int k = (tid & 511) << 2;
    const int m = r >> 9, b = r & 511;
    const float4 vv = *(const float4*)(x + ((size_t)(b * 4 + m)) * 2048 + k);
    ushort4 o;
    o.x = f2bf(fmaxf(vv.x, 0.f)); o.y = f2bf(fmaxf(vv.y, 0.f));
    o.z = f2bf(fmaxf(vv.z, 0.f)); o.w = f2bf(fmaxf(vv.w, 0.f));
    *(ushort4*)(xrb + (size_t)r * 2048 + k) = o;
  } else if (bid < 15360) {             // ---- w2t (round-5 body, flattened grid)
    const int idx = bid - 14336;
    const int s = idx >> 8, rem = idx & 255;
    const int rt = rem >> 3, ct = rem & 7;
    const float* src = (s == 0) ? w21 : (s == 1) ? w22 : (s == 2) ? w23 : w24;
    const int tr = threadIdx.x >> 4;
    const int tc = (threadIdx.x & 15) << 2;
#pragma unroll
    for (int i = 0; i < 4; ++i) {
      const float4 v = *(const float4*)(src + (size_t)(rt * 64 + tr + 16 * i) * 512 + ct * 64 + tc);
      lds[tr + 16 * i][tc + 0] = v.x; lds[tr + 16 * i][tc + 1] = v.y;
      lds[tr + 16 * i][tc + 2] = v.z; lds[tr + 16 * i][tc + 3] = v.w;
    }
    __syncthreads();
#pragma unroll
    for (int i = 0; i < 4; ++i) {
      ushort4 ov;
      ov.x = f2bf(lds[tc + 0][tr + 16 * i]); ov.y = f2bf(lds[tc + 1][tr + 16 * i]);
      ov.z = f2bf(lds[tc + 2][tr + 16 * i]); ov.w = f2bf(lds[tc + 3][tr + 16 * i]);
      *(ushort4*)(w2t + ((size_t)s * 512 + ct * 64 + tr + 16 * i) * 2048 + rt * 64 + tc) = ov;
    }
  } else if (bid < 16896) {             // ---- wen (round-5 body)
    const int tid = (bid - 15360) * 256 + threadIdx.x;
    const int r = tid >> 9;
    const int k = (tid & 511) << 2;
    float4 vv = make_float4(0.f, 0.f, 0.f, 0.f);
    if (r < 300)       vv = *(const float4*)(wemb + (size_t)r * 2048 + k);
    else if (r < 691)  vv = *(const float4*)(wnode + (size_t)(r - 300) * 2048 + k);
    ushort4 ov;
    ov.x = f2bf(vv.x); ov.y = f2bf(vv.y); ov.z = f2bf(vv.z); ov.w = f2bf(vv.w);
    *(ushort4*)(wen + (size_t)r * 2048 + k) = ov;
  } else {                              // ---- enb v2: block = one e, 4 dots
    const int e = bid - 16896;          // 0..767
    const int t8 = threadIdx.x << 3;    // 8 elems/thread
    float a0 = 0.f, a1 = 0.f, a2 = 0.f, a3 = 0.f;
    if (e < 691) {
      const float* row = (e < 300) ? (wemb + (size_t)e * 2048)
                                   : (wnode + (size_t)(e - 300) * 2048);
      const float4 r0 = *(const float4*)(row + t8);
      const float4 r1 = *(const float4*)(row + t8 + 4);
      const float4 c10 = *(const float4*)(b21 + t8), c11 = *(const float4*)(b21 + t8 + 4);
      const float4 c20 = *(const float4*)(b22 + t8), c21 = *(const float4*)(b22 + t8 + 4);
      const float4 c30 = *(const float4*)(b23 + t8), c31 = *(const float4*)(b23 + t8 + 4);
      const float4 c40 = *(const float4*)(b24 + t8), c41 = *(const float4*)(b24 + t8 + 4);
      a0 = r0.x*c10.x + r0.y*c10.y + r0.z*c10.z + r0.w*c10.w
         + r1.x*c11.x + r1.y*c11.y + r1.z*c11.z + r1.w*c11.w;
      a1 = r0.x*c20.x + r0.y*c20.y + r0.z*c20.z + r0.w*c20.w
         + r1.x*c21.x + r1.y*c21.y + r1.z*c21.z + r1.w*c21.w;
      a2 = r0.x*c30.x + r0.y*c30.y + r0.z*c30.z + r0.w*c30.w
         + r1.x*c31.x + r1.y*c31.y + r1.z*c31.z + r1.w*c31.w;
      a3 = r0.x*c40.x + r0.y*c40.y + r0.z*c40.z + r0.w*c40.w
         + r1.x*c41.x + r1.y*c41.y + r1.z*c41.z + r1.w*c41.w;
    }
#pragma unroll
    for (int off = 32; off; off >>= 1) {
      a0 += __shfl_down(a0, off); a1 += __shfl_down(a1, off);
      a2 += __shfl_down(a2, off); a3 += __shfl_down(a3, off);
    }
    const int wv = threadIdx.x >> 6;
    if ((threadIdx.x & 63) == 0) {
      red[wv][0] = a0; red[wv][1] = a1; red[wv][2] = a2; red[wv][3] = a3;
    }
    __syncthreads();
    if (threadIdx.x < 4) {
      const float v = red[0][threadIdx.x] + red[1][threadIdx.x] +
                      red[2][threadIdx.x] + red[3][threadIdx.x];
      ENb[(size_t)threadIdx.x * 768 + e] = (e < 691) ? v : 0.f;
    }
  }
}

// combine1 (round-5 proven)
__global__ __launch_bounds__(128) void combine1_k(const unsigned short* __restrict__ H0p,
                                                  unsigned short* __restrict__ h1,
                                                  const float* __restrict__ b11,
                                                  const float* __restrict__ b12,
                                                  const float* __restrict__ b13,
                                                  const float* __restrict__ b14) {
  const int cb = blockIdx.x;            // 0..7679 = c*512+b
  const int c = cb >> 9, b = cb & 511;
  const int s = (c < 4) ? 1 : (c < 10) ? 2 : (c < 14) ? 3 : 4;
  const unsigned char P[15][4] = {
    {0,0,0,0},{1,0,0,0},{2,0,0,0},{3,0,0,0},
    {4,7,0,0},{4,8,0,0},{4,9,0,0},{5,8,0,0},{5,9,0,0},{6,9,0,0},
    {10,12,14,0},{10,12,15,0},{10,13,15,0},{11,13,15,0},
    {16,17,18,19}};
  const float* b1 = (s == 1) ? b11 : (s == 2) ? b12 : (s == 3) ? b13 : b14;
  const int o = threadIdx.x << 2;
  float4 a = *(const float4*)(b1 + o);
  for (int t = 0; t < s; ++t) {
    const int p = P[c][t];
    const ushort4 hv = *(const ushort4*)(H0p + ((size_t)(p * 512 + b)) * 512 + o);
    a.x += bf2f(hv.x); a.y += bf2f(hv.y); a.z += bf2f(hv.z); a.w += bf2f(hv.w);
  }
  ushort4 ov;
  ov.x = f2bf(fmaxf(a.x, 0.f)); ov.y = f2bf(fmaxf(a.y, 0.f));
  ov.z = f2bf(fmaxf(a.z, 0.f)); ov.w = f2bf(fmaxf(a.w, 0.f));
  *(ushort4*)(h1 + (size_t)cb * 512 + o) = ov;
}

// combine2 (round-5 proven)
__global__ __launch_bounds__(256) void combine2_k(const float* __restrict__ EN0,
                                                  const float* __restrict__ b_emb,
                                                  const float* __restrict__ b_node,
                                                  float* __restrict__ out0,
                                                  float* __restrict__ out1) {
  const int b   = blockIdx.x;
  const int col = blockIdx.y * 256 + threadIdx.x;
  if (col >= 691) return;
  float vals[15];
#pragma unroll
  for (int j = 0; j < 15; ++j)
    vals[j] = EN0[((size_t)(j * 512 + b)) * 768 + col];
  const int MSK[15] = {1,2,4,8,3,5,9,6,10,12,7,11,13,14,15};
  if (col < 300) {
    const float be = b_emb[col];
#pragma unroll
    for (int i = 0; i < 15; ++i) {
      float sum = be;
#pragma unroll
      for (int j = 0; j < 15; ++j)
        if ((MSK[j] & MSK[i]) == MSK[j]) sum += vals[j];
      out0[((size_t)b * 15 + i) * 300 + col] = sum;
    }
  } else {
    const int v = col - 300;
    const float bn = b_node[v];
#pragma unroll
    for (int i = 0; i < 15; ++i) {
      float sum = bn;
#pragma unroll
      for (int j = 0; j < 15; ++j)
        if ((MSK[j] & MSK[i]) == MSK[j]) sum += vals[j];
      out1[((size_t)b * 391 + v) * 15 + i] = sum;
    }
  }
}

// ---------------------------------------------------------------------------
extern "C" void kernel_launch(void* const* d_in, const int* in_sizes, int n_in,
                              void* d_out, int out_size, void* d_ws, size_t ws_size,
                              hipStream_t stream) {
  const float* x     = (const float*)d_in[0];
  const float* w11   = (const float*)d_in[1];
  const float* b11   = (const float*)d_in[2];
  const float* w21   = (const float*)d_in[3];
  const float* b21   = (const float*)d_in[4];
  const float* w12   = (const float*)d_in[5];
  const float* b12   = (const float*)d_in[6];
  const float* w22   = (const float*)d_in[7];
  const float* b22   = (const float*)d_in[8];
  const float* w13   = (const float*)d_in[9];
  const float* b13   = (const float*)d_in[10];
  const float* w23   = (const float*)d_in[11];
  const float* b23   = (const float*)d_in[12];
  const float* w14   = (const float*)d_in[13];
  const float* b14   = (const float*)d_in[14];
  const float* w24   = (const float*)d_in[15];
  const float* b24   = (const float*)d_in[16];
  const float* wemb  = (const float*)d_in[17];
  const float* bemb  = (const float*)d_in[18];
  const float* wnode = (const float*)d_in[19];
  const float* bnode = (const float*)d_in[20];

  char* ws = (char*)d_ws;
  unsigned short* xrb   = (unsigned short*)(ws + 0);                 //  8,388,608
  unsigned short* w1cat = (unsigned short*)(ws + 8388608);           // -> 29,360,128
  unsigned short* w2t   = (unsigned short*)(ws + 29360128);          // -> 37,748,736
  unsigned short* wen   = (unsigned short*)(ws + 37748736);          // -> 40,894,464
  unsigned short* H0p   = (unsigned short*)(ws + 40894464);          // -> 51,380,224
  unsigned short* W2EN  = (unsigned short*)(ws + 51380224);          // -> 54,525,952
  float*          ENb   = (float*)(ws + 54525952);                   // -> 54,538,240
  unsigned short* h1bf  = (unsigned short*)(ws + 54538240);          // -> 62,402,560
  float*          EN0   = (float*)(ws + 0);                          // aliases xrb/w1cat

  float* out0 = (float*)d_out;            // embeddings (512,15,300)
  float* out1 = out0 + 2304000;           // node_out^T (512,391,15)

  prep_all_k<<<17664, 256, 0, stream>>>(x, w11, w12, w13, w14, w21, w22, w23, w24,
                                        wemb, wnode, b21, b22, b23, b24,
                                        xrb, w1cat, w2t, wen, ENb);
  mega1_k   <<<208, 512, 0, stream>>>(xrb, w1cat, wen, w2t, H0p, W2EN);
  combine1_k<<<7680, 128, 0, stream>>>(H0p, h1bf, b11, b12, b13, b14);
  gemmF_k   <<<dim3(6, 30), 512, 0, stream>>>(h1bf, W2EN, ENb, EN0);
  combine2_k<<<dim3(512, 3), 256, 0, stream>>>(EN0, bemb, bnode, out0, out1);
}